// Round 4
// baseline (1932.238 us; speedup 1.0000x reference)
//
#include <hip/hip_runtime.h>
#include <stdint.h>

#define NN_ 4096
#define DM_ 256

typedef unsigned short ushort_t;
typedef __bf16 bf16x8 __attribute__((ext_vector_type(8)));
typedef _Float16 f16x8 __attribute__((ext_vector_type(8)));
typedef float f32x4 __attribute__((ext_vector_type(4)));

__device__ __forceinline__ unsigned short f32_to_bf16(float x) {
  unsigned int u = __float_as_uint(x);
  unsigned int r = u + 0x7FFFu + ((u >> 16) & 1u);   // RNE
  return (unsigned short)(r >> 16);
}
__device__ __forceinline__ float bf16_to_f32(unsigned short h) {
  return __uint_as_float(((unsigned int)h) << 16);
}

// global -> LDS direct (16B/lane). LDS dest is wave-uniform base + lane*16.
__device__ __forceinline__ void async_cp16(const void* g, void* l) {
  auto gp = reinterpret_cast<__attribute__((address_space(1))) unsigned int*>(
      reinterpret_cast<uintptr_t>(g));
  auto lp = reinterpret_cast<__attribute__((address_space(3))) unsigned int*>(
      reinterpret_cast<uintptr_t>(l));
  __builtin_amdgcn_global_load_lds(gp, lp, 16, 0, 0);
}

// ---------------------------------------------------------------------------
// Kernel 1: Rt = rescale(dist)^T as fp16 hi/lo pair. Rt[p][m] = f(dist[m][p]).
// ---------------------------------------------------------------------------
__global__ __launch_bounds__(256) void rescale_kernel(const float* __restrict__ dist,
                                                      _Float16* __restrict__ Rth,
                                                      _Float16* __restrict__ Rtl) {
  __shared__ float tile[64][65];
  const int m0 = blockIdx.y * 64;
  const int p0 = blockIdx.x * 64;
  const int t = threadIdx.x;
  const int c = t & 63;
  const int rg = t >> 6;
  const float C = 3.718281828459045f;  // 1 + e
  for (int i = 0; i < 16; i++) {
    int ml = rg * 16 + i;
    float d = dist[(size_t)(m0 + ml) * NN_ + p0 + c];
    tile[c][ml] = C / (1.0f + expf(1.0f - d));  // store transposed into LDS
  }
  __syncthreads();
  for (int i = 0; i < 16; i++) {
    int pl = rg * 16 + i;
    float v = tile[pl][c];
    _Float16 hv = (_Float16)v;
    size_t o = (size_t)(p0 + pl) * NN_ + m0 + c;
    Rth[o] = hv;
    Rtl[o] = (_Float16)(v - (float)hv);
  }
}

// ---------------------------------------------------------------------------
// Kernel 2: O = X @ W^T (fp32 accum). Optional fp32 out, optional bf16 hi/lo.
// ---------------------------------------------------------------------------
__global__ __launch_bounds__(256) void proj_kernel(const float* __restrict__ X,
                                                   const float* __restrict__ W,
                                                   float* __restrict__ Of,
                                                   ushort_t* __restrict__ O1,
                                                   ushort_t* __restrict__ O2) {
  __shared__ float Xs[64][33];
  __shared__ float Ws[64][33];
  const int m0 = blockIdx.y * 64;
  const int n0 = blockIdx.x * 64;
  const int t = threadIdx.x;
  const int tm = t >> 4, tn = t & 15;
  float acc[4][4] = {};
  for (int k0 = 0; k0 < DM_; k0 += 32) {
    for (int q = 0; q < 2; q++) {
      int id = t + q * 256;
      int row = id >> 3;
      int c4 = (id & 7) * 4;
      float4 vx = *(const float4*)&X[(size_t)(m0 + row) * DM_ + k0 + c4];
      Xs[row][c4] = vx.x; Xs[row][c4 + 1] = vx.y; Xs[row][c4 + 2] = vx.z; Xs[row][c4 + 3] = vx.w;
      float4 vw = *(const float4*)&W[(size_t)(n0 + row) * DM_ + k0 + c4];
      Ws[row][c4] = vw.x; Ws[row][c4 + 1] = vw.y; Ws[row][c4 + 2] = vw.z; Ws[row][c4 + 3] = vw.w;
    }
    __syncthreads();
    for (int kk = 0; kk < 32; kk++) {
      float xi[4], wj[4];
      for (int i = 0; i < 4; i++) xi[i] = Xs[tm * 4 + i][kk];
      for (int j = 0; j < 4; j++) wj[j] = Ws[tn * 4 + j][kk];
      for (int i = 0; i < 4; i++)
        for (int j = 0; j < 4; j++) acc[i][j] += xi[i] * wj[j];
    }
    __syncthreads();
  }
  for (int i = 0; i < 4; i++)
    for (int j = 0; j < 4; j++) {
      size_t o = (size_t)(m0 + tm * 4 + i) * DM_ + n0 + tn * 4 + j;
      float v = acc[i][j];
      if (Of != nullptr) Of[o] = v;
      if (O1 != nullptr) {
        unsigned short hh = f32_to_bf16(v);
        O1[o] = hh;
        O2[o] = f32_to_bf16(v - bf16_to_f32(hh));
      }
    }
}

// ---------------------------------------------------------------------------
// Kernel 3: per head, A = relu(Q_h K_h^T)/sqrt(32), 3-product bf16 (exact-ish),
// output as fp16 hi/lo pair. Block (0,0) also zeroes rowMax for this head.
// ---------------------------------------------------------------------------
__global__ __launch_bounds__(256) void qk_kernel(const ushort_t* __restrict__ Q1,
                                                 const ushort_t* __restrict__ Q2,
                                                 const ushort_t* __restrict__ K1,
                                                 const ushort_t* __restrict__ K2,
                                                 _Float16* __restrict__ Ah,
                                                 _Float16* __restrict__ Al,
                                                 float* __restrict__ rowMax, int h) {
  const int n0 = blockIdx.y * 64;  // rows (n, from Q)
  const int m0 = blockIdx.x * 64;  // cols (m, from K)
  const int t = threadIdx.x;
  if (blockIdx.x == 0 && blockIdx.y == 0) {
    for (int i = t; i < NN_; i += 256) rowMax[i] = 0.f;
  }
  const int wave = t >> 6, lane = t & 63;
  const int wm = wave >> 1, wn = wave & 1;
  const int r16 = lane & 15, quad = lane >> 4;
  const int ho = h * 32 + quad * 8;
  f32x4 acc[2][2] = {};
  bf16x8 a1[2], a2[2], b1[2], b2[2];
  for (int i = 0; i < 2; i++) {
    int row = n0 + wm * 32 + i * 16 + r16;
    a1[i] = *(const bf16x8*)&Q1[(size_t)row * DM_ + ho];
    a2[i] = *(const bf16x8*)&Q2[(size_t)row * DM_ + ho];
  }
  for (int j = 0; j < 2; j++) {
    int col = m0 + wn * 32 + j * 16 + r16;
    b1[j] = *(const bf16x8*)&K1[(size_t)col * DM_ + ho];
    b2[j] = *(const bf16x8*)&K2[(size_t)col * DM_ + ho];
  }
  for (int i = 0; i < 2; i++)
    for (int j = 0; j < 2; j++) {
      acc[i][j] = __builtin_amdgcn_mfma_f32_16x16x32_bf16(a1[i], b1[j], acc[i][j], 0, 0, 0);
      acc[i][j] = __builtin_amdgcn_mfma_f32_16x16x32_bf16(a1[i], b2[j], acc[i][j], 0, 0, 0);
      acc[i][j] = __builtin_amdgcn_mfma_f32_16x16x32_bf16(a2[i], b1[j], acc[i][j], 0, 0, 0);
    }
  const float scale = 0.17677669529663688f;  // 1/sqrt(32)
  for (int i = 0; i < 2; i++)
    for (int j = 0; j < 2; j++)
      for (int r = 0; r < 4; r++) {
        int row = n0 + wm * 32 + i * 16 + quad * 4 + r;  // C/D: col=lane&15, row=quad*4+reg
        int col = m0 + wn * 32 + j * 16 + r16;
        float w = acc[i][j][r] * scale;
        w = w > 0.f ? w : 0.f;
        _Float16 hh = (_Float16)w;
        size_t o = (size_t)row * NN_ + col;
        Ah[o] = hh;
        Al[o] = (_Float16)(w - (float)hh);
      }
}

// ---------------------------------------------------------------------------
// Kernel 4: S~ = Ah @ Rth^T (NT, K=4096), fp16 MFMA.
// 256x256 tile, BK=64, 512 threads (8 waves, 2Mx4N), register-reuse phases
// (24 ds_read_b128 / wave / K-tile) -- now FREE-RUNNING within a K-tile:
// with register reuse, all 4 phases read only buffer X and stage only into
// buffer Y, so there is no intra-K-tile cross-wave hazard. Barriers exist
// ONLY at K-tile boundaries:
//   barrier1: all waves done reading X (their lgkm drained before their last
//             MFMA issue) -> safe to stage tile tt+2 into X
//   vmcnt(8): per-wave, its tile-tt+1 loads (issued last iter, FIFO) retired
//   barrier2: ALL waves' tile-tt+1 loads retired -> buf Y fully populated
// This lets waves skew within the K-tile so the CU-shared LDS pipe (~2304cy)
// and per-SIMD MFMA pipes (~2483cy) overlap (max, not sum). Round-3 counters
// showed they were summing (4988cy/K-tile) under the 8-barrier lockstep.
// LDS: 2 x (A 256x64 + B 256x64) fp16 = 128 KiB. Chunk-XOR swizzle
// (0-conflict): chunk c of row r at slot c^(r&7); staging pre-swizzles the
// per-lane GLOBAL chunk (lane&7)^srow. setprio(1) around MFMA clusters.
// ---------------------------------------------------------------------------
template <int SLOT>
__device__ __forceinline__ void stage_half(const _Float16* __restrict__ Ah,
                                           const _Float16* __restrict__ Rth,
                                           int m0, int p0, _Float16* sAY, _Float16* sBY,
                                           int tn, int wave, int srow, int cg) {
  const _Float16* src = (SLOT == 0 || SLOT == 3) ? Ah : Rth;
  const int gr0 = ((SLOT == 0 || SLOT == 3) ? m0 : p0) + ((SLOT >= 2) ? 128 : 0);
  _Float16* dst = ((SLOT == 0 || SLOT == 3) ? sAY : sBY) + ((SLOT >= 2) ? 128 * 64 : 0);
  const int k0 = tn * 64;
#pragma unroll
  for (int q = 0; q < 2; q++) {
    const int rl = wave * 16 + q * 8;  // wave-uniform slab base (8 rows x 64 f16)
    async_cp16(&src[(size_t)(gr0 + rl + srow) * NN_ + k0 + cg * 8], dst + rl * 64);
  }
}

template <int QM>
__device__ __forceinline__ void read_af(const _Float16* sAX, int wr, int r16, int quad,
                                        f16x8 (&af)[4][2]) {
#pragma unroll
  for (int i = 0; i < 4; i++) {
    int ar = QM * 128 + wr * 64 + i * 16 + r16;
    const _Float16* base = sAX + ar * 64;
    int x = ar & 7;
    af[i][0] = *(const f16x8*)(base + (quad ^ x) * 8);
    af[i][1] = *(const f16x8*)(base + ((4 + quad) ^ x) * 8);
  }
}

template <int QN>
__device__ __forceinline__ void read_bg(const _Float16* sBX, int wc, int r16, int quad,
                                        f16x8 (&bg)[2][2]) {
#pragma unroll
  for (int j = 0; j < 2; j++) {
    int br = QN * 128 + wc * 32 + j * 16 + r16;
    const _Float16* base = sBX + br * 64;
    int x = br & 7;
    bg[j][0] = *(const f16x8*)(base + (quad ^ x) * 8);
    bg[j][1] = *(const f16x8*)(base + ((4 + quad) ^ x) * 8);
  }
}

template <int P>
__device__ __forceinline__ void phase_mac(f32x4 (&acc)[4][4][2],
                                          f16x8 (&af)[4][2], f16x8 (&bg)[2][2]) {
#pragma unroll
  for (int i = 0; i < 4; i++)
#pragma unroll
    for (int j = 0; j < 2; j++) {
      acc[P][i][j] = __builtin_amdgcn_mfma_f32_16x16x32_f16(af[i][0], bg[j][0], acc[P][i][j], 0, 0, 0);
      acc[P][i][j] = __builtin_amdgcn_mfma_f32_16x16x32_f16(af[i][1], bg[j][1], acc[P][i][j], 0, 0, 0);
    }
}

__global__ __launch_bounds__(512, 2) void sgemm_kernel(const _Float16* __restrict__ Ah,
                                                       const _Float16* __restrict__ Rth,
                                                       _Float16* __restrict__ Sh,
                                                       float* __restrict__ rowMax) {
  __shared__ _Float16 sA[2][256 * 64];  // 32 KB per buffer
  __shared__ _Float16 sB[2][256 * 64];
  // XCD-aware bijective swizzle: 256 wgs, 8 XCDs, 32 contiguous tiles per XCD.
  const int b = blockIdx.x;
  const int swz = (b & 7) * 32 + (b >> 3);
  const int m0 = (swz >> 4) * 256;
  const int p0 = (swz & 15) * 256;
  const int tid = threadIdx.x;
  const int wave = tid >> 6, lane = tid & 63;
  const int wr = wave >> 2, wc = wave & 3;   // 2M x 4N wave grid
  const int r16 = lane & 15, quad = lane >> 4;
  const int srow = lane >> 3;            // row within 8-row staging slab
  const int cg = (lane & 7) ^ srow;      // pre-swizzled global chunk

  f32x4 acc[4][4][2] = {};               // [quadrant][i][j]

  // stage a full K-tile (4 slots x 2 loads = 8 per wave) into buffer `buf`
  auto STAGE = [&](int buf, int tile) {
    stage_half<0>(Ah, Rth, m0, p0, sA[buf], sB[buf], tile, wave, srow, cg);
    stage_half<1>(Ah, Rth, m0, p0, sA[buf], sB[buf], tile, wave, srow, cg);
    stage_half<2>(Ah, Rth, m0, p0, sA[buf], sB[buf], tile, wave, srow, cg);
    stage_half<3>(Ah, Rth, m0, p0, sA[buf], sB[buf], tile, wave, srow, cg);
  };

  // compute one K-tile from buffer X: register-reuse phase order, no barriers
  auto COMPUTE = [&](int X) {
    f16x8 af[4][2], bg0[2][2], bg1[2][2];
    read_af<0>(sA[X], wr, r16, quad, af);
    read_bg<0>(sB[X], wc, r16, quad, bg0);
    __builtin_amdgcn_s_setprio(1);
    phase_mac<0>(acc, af, bg0);
    __builtin_amdgcn_s_setprio(0);
    read_bg<1>(sB[X], wc, r16, quad, bg1);
    __builtin_amdgcn_s_setprio(1);
    phase_mac<1>(acc, af, bg1);
    __builtin_amdgcn_s_setprio(0);
    read_af<1>(sA[X], wr, r16, quad, af);
    __builtin_amdgcn_s_setprio(1);
    phase_mac<2>(acc, af, bg0);
    phase_mac<3>(acc, af, bg1);
    __builtin_amdgcn_s_setprio(0);
  };

  // prologue: tiles 0,1 in flight; wait tile 0 (8 newest outstanding = tile 1)
  STAGE(0, 0);
  STAGE(1, 1);
  asm volatile("s_waitcnt vmcnt(8)" ::: "memory");
  asm volatile("s_barrier" ::: "memory");

  for (int tt = 0; tt < 62; ++tt) {
    const int X = tt & 1;
    COMPUTE(X);
    asm volatile("s_barrier" ::: "memory");        // all waves done reading X
    STAGE(X, tt + 2);                              // overwrite X with tile tt+2
    asm volatile("s_waitcnt vmcnt(8)" ::: "memory"); // my tile-(tt+1) loads done
    asm volatile("s_barrier" ::: "memory");        // everyone's tile-(tt+1) done
  }
  COMPUTE(0);                                      // tile 62 (buf 0)
  asm volatile("s_barrier" ::: "memory");
  asm volatile("s_waitcnt vmcnt(0)" ::: "memory"); // tile 63 loads done
  asm volatile("s_barrier" ::: "memory");
  COMPUTE(1);                                      // tile 63 (buf 1)

  // epilogue: per-row max over the full 256-wide block -> atomicMax
#pragma unroll
  for (int qm = 0; qm < 2; qm++)
#pragma unroll
    for (int i = 0; i < 4; i++)
#pragma unroll
      for (int r = 0; r < 4; r++) {
        float mv = acc[qm * 2][i][0][r];
        mv = fmaxf(mv, acc[qm * 2][i][1][r]);
        mv = fmaxf(mv, acc[qm * 2 + 1][i][0][r]);
        mv = fmaxf(mv, acc[qm * 2 + 1][i][1][r]);
        for (int off = 1; off < 16; off <<= 1) mv = fmaxf(mv, __shfl_xor(mv, off, 64));
        if (r16 == 0) {
          int row = m0 + qm * 128 + wr * 64 + i * 16 + quad * 4 + r;
          atomicMax((unsigned int*)&rowMax[row], __float_as_uint(mv));
        }
      }
  // fp16 store of the tile
#pragma unroll
  for (int p = 0; p < 4; p++) {
    const int qm = p >> 1, qn = p & 1;
#pragma unroll
    for (int i = 0; i < 4; i++)
#pragma unroll
      for (int j = 0; j < 2; j++)
#pragma unroll
        for (int r = 0; r < 4; r++) {
          int row = m0 + qm * 128 + wr * 64 + i * 16 + quad * 4 + r;
          int col = p0 + qn * 128 + wc * 32 + j * 16 + r16;
          Sh[(size_t)row * NN_ + col] = (_Float16)acc[p][i][j][r];
        }
  }
}

// ---------------------------------------------------------------------------
// Kernel 5: one BLOCK (4 waves) per row. Each wave scans 1/4 of the S~ row
// for candidates (S~ > rowMax-16) into a shared list; candidates are then
// distributed across waves (j = wave, wave+4, ...), each wave keeping its own
// online-softmax state (m, l, o); final flash-merge via LDS. Exact candidate
// scores: fp32 dot of (Ah+Al) x (Rth+Rtl), 64-lane shuffle reduce.
// ---------------------------------------------------------------------------
__global__ __launch_bounds__(256) void refine_kernel(const _Float16* __restrict__ Sh,
                                                     const float* __restrict__ rowMax,
                                                     const _Float16* __restrict__ Ah,
                                                     const _Float16* __restrict__ Al,
                                                     const _Float16* __restrict__ Rth,
                                                     const _Float16* __restrict__ Rtl,
                                                     const float* __restrict__ Vf,
                                                     float* __restrict__ out, int h) {
  __shared__ int plist[64];
  __shared__ int cnt;
  __shared__ float mW[4], lW[4];
  __shared__ float oW[4][32];
  const int t = threadIdx.x;
  const int wave = t >> 6, lane = t & 63;
  const int n = blockIdx.x;
  if (t == 0) cnt = 0;
  __syncthreads();
  const float thr = rowMax[n] - 16.0f;
  const _Float16* srow = Sh + (size_t)n * NN_;
  // each wave scans 2 of the 8 chunks (1024 elements)
  for (int q = 0; q < 2; q++) {
    int it = wave * 2 + q;
    f16x8 v = *(const f16x8*)&srow[it * 512 + lane * 8];
#pragma unroll
    for (int e = 0; e < 8; e++) {
      if ((float)v[e] > thr) {
        int idx = atomicAdd(&cnt, 1);
        if (idx < 64) plist[idx] = it * 512 + lane * 8 + e;
      }
    }
  }
  __syncthreads();
  int C = cnt;
  if (C > 64) C = 64;
  const _Float16* arh = Ah + (size_t)n * NN_;
  const _Float16* arl = Al + (size_t)n * NN_;
  float mcur = -1e30f, lsum = 0.f, oacc = 0.f;
  for (int j = wave; j < C; j += 4) {
    int p = plist[j];
    const _Float16* rh = Rth + (size_t)p * NN_;
    const _Float16* rl = Rtl + (size_t)p * NN_;
    float d = 0.f;
#pragma unroll
    for (int it = 0; it < 8; it++) {
      int m = it * 512 + lane * 8;
      f16x8 a8 = *(const f16x8*)&arh[m];
      f16x8 l8 = *(const f16x8*)&arl[m];
      f16x8 c8 = *(const f16x8*)&rh[m];
      f16x8 e8 = *(const f16x8*)&rl[m];
#pragma unroll
      for (int e = 0; e < 8; e++)
        d += ((float)a8[e] + (float)l8[e]) * ((float)c8[e] + (float)e8[e]);
    }
    for (int off = 32; off > 0; off >>= 1) d += __shfl_xor(d, off, 64);
    float vval = (lane < 32) ? Vf[(size_t)p * DM_ + h * 32 + lane] : 0.f;
    float nm = fmaxf(mcur, d);
    float alpha = __expf(mcur - nm);
    float w = __expf(d - nm);
    lsum = lsum * alpha + w;
    oacc = oacc * alpha + w * vval;
    mcur = nm;
  }
  if (lane == 0) { mW[wave] = mcur; lW[wave] = lsum; }
  if (lane < 32) oW[wave][lane] = oacc;
  __syncthreads();
  if (wave == 0 && lane < 32) {
    float M = fmaxf(fmaxf(mW[0], mW[1]), fmaxf(mW[2], mW[3]));
    float l = 0.f, o = 0.f;
#pragma unroll
    for (int w = 0; w < 4; w++) {
      float al = __expf(mW[w] - M);
      l += lW[w] * al;
      o += oW[w][lane] * al;
    }
    out[(size_t)n * DM_ + h * 32 + lane] = o / l;
  }
}

// ---------------------------------------------------------------------------
extern "C" void kernel_launch(void* const* d_in, const int* in_sizes, int n_in,
                              void* d_out, int out_size, void* d_ws, size_t ws_size,
                              hipStream_t stream) {
  const float* inQ = (const float*)d_in[0];
  const float* inK = (const float*)d_in[1];
  const float* inV = (const float*)d_in[2];
  // d_in[3] = adj_matrix: dead code in the reference
  const float* dist = (const float*)d_in[4];
  const float* WQ = (const float*)d_in[5];
  const float* WK = (const float*)d_in[6];
  const float* WV = (const float*)d_in[7];
  float* out = (float*)d_out;

  const size_t ND = (size_t)NN_ * DM_;   // 1M
  const size_t NSQ = (size_t)NN_ * NN_;  // 16.7M
  // ws layout (~172 MiB total; 212 MiB proven available in round 1):
  float* Vf = (float*)d_ws;              // 4 MiB
  ushort_t* Q1 = (ushort_t*)(Vf + ND);   // 2 MiB each
  ushort_t* Q2 = Q1 + ND;
  ushort_t* K1 = Q2 + ND;
  ushort_t* K2 = K1 + ND;
  _Float16* Rth = (_Float16*)(K2 + ND);  // 32 MiB each
  _Float16* Rtl = Rth + NSQ;
  _Float16* Ah = Rtl + NSQ;              // per-head reuse, 32 MiB each
  _Float16* Al = Ah + NSQ;
  _Float16* Sh = Al + NSQ;               // 32 MiB
  float* rowMax = (float*)(Sh + NSQ);    // 16 KiB

  rescale_kernel<<<dim3(64, 64), 256, 0, stream>>>(dist, Rth, Rtl);
  proj_kernel<<<dim3(4, 64), 256, 0, stream>>>(inQ, WQ, (float*)nullptr, Q1, Q2);
  proj_kernel<<<dim3(4, 64), 256, 0, stream>>>(inK, WK, (float*)nullptr, K1, K2);
  proj_kernel<<<dim3(4, 64), 256, 0, stream>>>(inV, WV, Vf, (ushort_t*)nullptr, (ushort_t*)nullptr);
  for (int h = 0; h < 8; h++) {
    qk_kernel<<<dim3(64, 64), 256, 0, stream>>>(Q1, Q2, K1, K2, Ah, Al, rowMax, h);
    sgemm_kernel<<<dim3(256), dim3(512), 0, stream>>>(Ah, Rth, Sh, rowMax);
    refine_kernel<<<NN_, 256, 0, stream>>>(Sh, rowMax, Ah, Al, Rth, Rtl, Vf, out, h);
  }
}

// Round 7
// 1865.278 us; speedup vs baseline: 1.0359x; 1.0359x over previous
//
#include <hip/hip_runtime.h>
#include <stdint.h>

#define NN_ 4096
#define DM_ 256

typedef unsigned short ushort_t;
typedef __bf16 bf16x8 __attribute__((ext_vector_type(8)));
typedef _Float16 f16x8 __attribute__((ext_vector_type(8)));
typedef float f32x4 __attribute__((ext_vector_type(4)));

__device__ __forceinline__ unsigned short f32_to_bf16(float x) {
  unsigned int u = __float_as_uint(x);
  unsigned int r = u + 0x7FFFu + ((u >> 16) & 1u);   // RNE
  return (unsigned short)(r >> 16);
}
__device__ __forceinline__ float bf16_to_f32(unsigned short h) {
  return __uint_as_float(((unsigned int)h) << 16);
}

// global -> LDS direct (16B/lane). LDS dest is wave-uniform base + lane*16.
__device__ __forceinline__ void async_cp16(const void* g, void* l) {
  auto gp = reinterpret_cast<__attribute__((address_space(1))) unsigned int*>(
      reinterpret_cast<uintptr_t>(g));
  auto lp = reinterpret_cast<__attribute__((address_space(3))) unsigned int*>(
      reinterpret_cast<uintptr_t>(l));
  __builtin_amdgcn_global_load_lds(gp, lp, 16, 0, 0);
}

// ---------------------------------------------------------------------------
// Kernel 1: Rt = rescale(dist)^T as fp16 hi/lo pair. Rt[p][m] = f(dist[m][p]).
// ---------------------------------------------------------------------------
__global__ __launch_bounds__(256) void rescale_kernel(const float* __restrict__ dist,
                                                      _Float16* __restrict__ Rth,
                                                      _Float16* __restrict__ Rtl) {
  __shared__ float tile[64][65];
  const int m0 = blockIdx.y * 64;
  const int p0 = blockIdx.x * 64;
  const int t = threadIdx.x;
  const int c = t & 63;
  const int rg = t >> 6;
  const float C = 3.718281828459045f;  // 1 + e
  for (int i = 0; i < 16; i++) {
    int ml = rg * 16 + i;
    float d = dist[(size_t)(m0 + ml) * NN_ + p0 + c];
    tile[c][ml] = C / (1.0f + expf(1.0f - d));  // store transposed into LDS
  }
  __syncthreads();
  for (int i = 0; i < 16; i++) {
    int pl = rg * 16 + i;
    float v = tile[pl][c];
    _Float16 hv = (_Float16)v;
    size_t o = (size_t)(p0 + pl) * NN_ + m0 + c;
    Rth[o] = hv;
    Rtl[o] = (_Float16)(v - (float)hv);
  }
}

// ---------------------------------------------------------------------------
// Kernel 2: O = X @ W^T (fp32 accum). Optional fp32 out, optional bf16 hi/lo.
// ---------------------------------------------------------------------------
__global__ __launch_bounds__(256) void proj_kernel(const float* __restrict__ X,
                                                   const float* __restrict__ W,
                                                   float* __restrict__ Of,
                                                   ushort_t* __restrict__ O1,
                                                   ushort_t* __restrict__ O2) {
  __shared__ float Xs[64][33];
  __shared__ float Ws[64][33];
  const int m0 = blockIdx.y * 64;
  const int n0 = blockIdx.x * 64;
  const int t = threadIdx.x;
  const int tm = t >> 4, tn = t & 15;
  float acc[4][4] = {};
  for (int k0 = 0; k0 < DM_; k0 += 32) {
    for (int q = 0; q < 2; q++) {
      int id = t + q * 256;
      int row = id >> 3;
      int c4 = (id & 7) * 4;
      float4 vx = *(const float4*)&X[(size_t)(m0 + row) * DM_ + k0 + c4];
      Xs[row][c4] = vx.x; Xs[row][c4 + 1] = vx.y; Xs[row][c4 + 2] = vx.z; Xs[row][c4 + 3] = vx.w;
      float4 vw = *(const float4*)&W[(size_t)(n0 + row) * DM_ + k0 + c4];
      Ws[row][c4] = vw.x; Ws[row][c4 + 1] = vw.y; Ws[row][c4 + 2] = vw.z; Ws[row][c4 + 3] = vw.w;
    }
    __syncthreads();
    for (int kk = 0; kk < 32; kk++) {
      float xi[4], wj[4];
      for (int i = 0; i < 4; i++) xi[i] = Xs[tm * 4 + i][kk];
      for (int j = 0; j < 4; j++) wj[j] = Ws[tn * 4 + j][kk];
      for (int i = 0; i < 4; i++)
        for (int j = 0; j < 4; j++) acc[i][j] += xi[i] * wj[j];
    }
    __syncthreads();
  }
  for (int i = 0; i < 4; i++)
    for (int j = 0; j < 4; j++) {
      size_t o = (size_t)(m0 + tm * 4 + i) * DM_ + n0 + tn * 4 + j;
      float v = acc[i][j];
      if (Of != nullptr) Of[o] = v;
      if (O1 != nullptr) {
        unsigned short hh = f32_to_bf16(v);
        O1[o] = hh;
        O2[o] = f32_to_bf16(v - bf16_to_f32(hh));
      }
    }
}

// ---------------------------------------------------------------------------
// Kernel 3: per head, A = relu(Q_h K_h^T)/sqrt(32), 3-product bf16 (exact-ish),
// output as fp16 hi/lo pair. Block (0,0) also zeroes rowMax for this head.
// ---------------------------------------------------------------------------
__global__ __launch_bounds__(256) void qk_kernel(const ushort_t* __restrict__ Q1,
                                                 const ushort_t* __restrict__ Q2,
                                                 const ushort_t* __restrict__ K1,
                                                 const ushort_t* __restrict__ K2,
                                                 _Float16* __restrict__ Ah,
                                                 _Float16* __restrict__ Al,
                                                 float* __restrict__ rowMax, int h) {
  const int n0 = blockIdx.y * 64;  // rows (n, from Q)
  const int m0 = blockIdx.x * 64;  // cols (m, from K)
  const int t = threadIdx.x;
  if (blockIdx.x == 0 && blockIdx.y == 0) {
    for (int i = t; i < NN_; i += 256) rowMax[i] = 0.f;
  }
  const int wave = t >> 6, lane = t & 63;
  const int wm = wave >> 1, wn = wave & 1;
  const int r16 = lane & 15, quad = lane >> 4;
  const int ho = h * 32 + quad * 8;
  f32x4 acc[2][2] = {};
  bf16x8 a1[2], a2[2], b1[2], b2[2];
  for (int i = 0; i < 2; i++) {
    int row = n0 + wm * 32 + i * 16 + r16;
    a1[i] = *(const bf16x8*)&Q1[(size_t)row * DM_ + ho];
    a2[i] = *(const bf16x8*)&Q2[(size_t)row * DM_ + ho];
  }
  for (int j = 0; j < 2; j++) {
    int col = m0 + wn * 32 + j * 16 + r16;
    b1[j] = *(const bf16x8*)&K1[(size_t)col * DM_ + ho];
    b2[j] = *(const bf16x8*)&K2[(size_t)col * DM_ + ho];
  }
  for (int i = 0; i < 2; i++)
    for (int j = 0; j < 2; j++) {
      acc[i][j] = __builtin_amdgcn_mfma_f32_16x16x32_bf16(a1[i], b1[j], acc[i][j], 0, 0, 0);
      acc[i][j] = __builtin_amdgcn_mfma_f32_16x16x32_bf16(a1[i], b2[j], acc[i][j], 0, 0, 0);
      acc[i][j] = __builtin_amdgcn_mfma_f32_16x16x32_bf16(a2[i], b1[j], acc[i][j], 0, 0, 0);
    }
  const float scale = 0.17677669529663688f;  // 1/sqrt(32)
  for (int i = 0; i < 2; i++)
    for (int j = 0; j < 2; j++)
      for (int r = 0; r < 4; r++) {
        int row = n0 + wm * 32 + i * 16 + quad * 4 + r;  // C/D: col=lane&15, row=quad*4+reg
        int col = m0 + wn * 32 + j * 16 + r16;
        float w = acc[i][j][r] * scale;
        w = w > 0.f ? w : 0.f;
        _Float16 hh = (_Float16)w;
        size_t o = (size_t)row * NN_ + col;
        Ah[o] = hh;
        Al[o] = (_Float16)(w - (float)hh);
      }
}

// ---------------------------------------------------------------------------
// Kernel 4: S~ = Ah @ Rth^T (NT, K=4096), fp16 MFMA.
// 256x256 tile, BK=64, 512 threads (8 waves, 2Mx4N), register-reuse phases
// (24 ds_read_b128 / wave / K-tile). Round-5 schedule (revert of round-4's
// free-run; two deltas vs the 133us round-3 structure):
//  1. ALL 8 stage loads issued at phase 0; ONE vmcnt(0) wait at phase 3
//     (3 MFMA windows ~950cy after issue, hiding HBM-miss latency that the
//     per-phase vmcnt(4) waits exposed at ~600cy lead).
//  2. Post-MFMA barriers dropped; each phase keeps its PRE-MFMA barrier, so
//     skew is bounded to one phase (NOT round-4 free-run) but a fast wave's
//     ds_reads overlap a slow wave's MFMA window (LDS pipe under matrix pipe).
// Hazards: buf Y's last read (ph2 af) is lgkm-drained before ph2-MFMA, which
// precedes every wave's ph3-barrier arrival, which precedes any tile-tt+1
// stage into Y. Tile-tt+1 data confirmed by per-wave vmcnt(0) + ph3 barrier.
// LDS: 2 x (A 256x64 + B 256x64) fp16 = 128 KiB. Chunk-XOR swizzle
// (0-conflict proven): chunk c of row r at slot c^(r&7); staging pre-swizzles
// the per-lane GLOBAL chunk (lane&7)^srow. setprio(1) around MFMA clusters.
// ---------------------------------------------------------------------------
template <int SLOT>
__device__ __forceinline__ void stage_half(const _Float16* __restrict__ Ah,
                                           const _Float16* __restrict__ Rth,
                                           int m0, int p0, _Float16* sAY, _Float16* sBY,
                                           int tn, int wave, int srow, int cg) {
  const _Float16* src = (SLOT == 0 || SLOT == 3) ? Ah : Rth;
  const int gr0 = ((SLOT == 0 || SLOT == 3) ? m0 : p0) + ((SLOT >= 2) ? 128 : 0);
  _Float16* dst = ((SLOT == 0 || SLOT == 3) ? sAY : sBY) + ((SLOT >= 2) ? 128 * 64 : 0);
  const int k0 = tn * 64;
#pragma unroll
  for (int q = 0; q < 2; q++) {
    const int rl = wave * 16 + q * 8;  // wave-uniform slab base (8 rows x 64 f16)
    async_cp16(&src[(size_t)(gr0 + rl + srow) * NN_ + k0 + cg * 8], dst + rl * 64);
  }
}

template <int QM>
__device__ __forceinline__ void read_af(const _Float16* sAX, int wr, int r16, int quad,
                                        f16x8 (&af)[4][2]) {
#pragma unroll
  for (int i = 0; i < 4; i++) {
    int ar = QM * 128 + wr * 64 + i * 16 + r16;
    const _Float16* base = sAX + ar * 64;
    int x = ar & 7;
    af[i][0] = *(const f16x8*)(base + (quad ^ x) * 8);
    af[i][1] = *(const f16x8*)(base + ((4 + quad) ^ x) * 8);
  }
}

template <int QN>
__device__ __forceinline__ void read_bg(const _Float16* sBX, int wc, int r16, int quad,
                                        f16x8 (&bg)[2][2]) {
#pragma unroll
  for (int j = 0; j < 2; j++) {
    int br = QN * 128 + wc * 32 + j * 16 + r16;
    const _Float16* base = sBX + br * 64;
    int x = br & 7;
    bg[j][0] = *(const f16x8*)(base + (quad ^ x) * 8);
    bg[j][1] = *(const f16x8*)(base + ((4 + quad) ^ x) * 8);
  }
}

template <int P>
__device__ __forceinline__ void phase_mac(f32x4 (&acc)[4][4][2],
                                          f16x8 (&af)[4][2], f16x8 (&bg)[2][2]) {
#pragma unroll
  for (int i = 0; i < 4; i++)
#pragma unroll
    for (int j = 0; j < 2; j++) {
      acc[P][i][j] = __builtin_amdgcn_mfma_f32_16x16x32_f16(af[i][0], bg[j][0], acc[P][i][j], 0, 0, 0);
      acc[P][i][j] = __builtin_amdgcn_mfma_f32_16x16x32_f16(af[i][1], bg[j][1], acc[P][i][j], 0, 0, 0);
    }
}

__global__ __launch_bounds__(512, 2) void sgemm_kernel(const _Float16* __restrict__ Ah,
                                                       const _Float16* __restrict__ Rth,
                                                       _Float16* __restrict__ Sh,
                                                       float* __restrict__ rowMax) {
  __shared__ _Float16 sA[2][256 * 64];  // 32 KB per buffer
  __shared__ _Float16 sB[2][256 * 64];
  // XCD-aware bijective swizzle: 256 wgs, 8 XCDs, 32 contiguous tiles per XCD.
  const int b = blockIdx.x;
  const int swz = (b & 7) * 32 + (b >> 3);
  const int m0 = (swz >> 4) * 256;
  const int p0 = (swz & 15) * 256;
  const int tid = threadIdx.x;
  const int wave = tid >> 6, lane = tid & 63;
  const int wr = wave >> 2, wc = wave & 3;   // 2M x 4N wave grid
  const int r16 = lane & 15, quad = lane >> 4;
  const int srow = lane >> 3;            // row within 8-row staging slab
  const int cg = (lane & 7) ^ srow;      // pre-swizzled global chunk

  f32x4 acc[4][4][2] = {};               // [quadrant][i][j]

  // stage a full K-tile (4 slots x 2 loads = 8 per wave) into buffer `buf`
  auto STAGE = [&](int buf, int tile) {
    stage_half<0>(Ah, Rth, m0, p0, sA[buf], sB[buf], tile, wave, srow, cg);
    stage_half<1>(Ah, Rth, m0, p0, sA[buf], sB[buf], tile, wave, srow, cg);
    stage_half<2>(Ah, Rth, m0, p0, sA[buf], sB[buf], tile, wave, srow, cg);
    stage_half<3>(Ah, Rth, m0, p0, sA[buf], sB[buf], tile, wave, srow, cg);
  };

  // prologue: tile 0 -> buf 0
  STAGE(0, 0);
  asm volatile("s_waitcnt vmcnt(0)" ::: "memory");
  asm volatile("s_barrier" ::: "memory");

  for (int tt = 0; tt < 63; ++tt) {      // compute tile tt, stage tile tt+1
    const int X = tt & 1, Y = X ^ 1;
    f16x8 af[4][2], bg0[2][2], bg1[2][2];
    // ---- phase 0: stage whole next tile, read af0+bg0, mac quad(0,0) ----
    STAGE(Y, tt + 1);
    read_af<0>(sA[X], wr, r16, quad, af);
    read_bg<0>(sB[X], wc, r16, quad, bg0);
    asm volatile("s_barrier" ::: "memory");
    __builtin_amdgcn_s_setprio(1);
    phase_mac<0>(acc, af, bg0);
    __builtin_amdgcn_s_setprio(0);
    // ---- phase 1: read bg1, mac quad(0,1) [af reused] ----
    read_bg<1>(sB[X], wc, r16, quad, bg1);
    asm volatile("s_barrier" ::: "memory");
    __builtin_amdgcn_s_setprio(1);
    phase_mac<1>(acc, af, bg1);
    __builtin_amdgcn_s_setprio(0);
    // ---- phase 2: read af1 (overwrite), mac quad(1,0) [bg0 reused] ----
    read_af<1>(sA[X], wr, r16, quad, af);
    asm volatile("s_barrier" ::: "memory");
    __builtin_amdgcn_s_setprio(1);
    phase_mac<2>(acc, af, bg0);
    __builtin_amdgcn_s_setprio(0);
    // ---- phase 3: wait next-tile loads, mac quad(1,1) [af+bg1 reused] ----
    asm volatile("s_waitcnt vmcnt(0)" ::: "memory");
    asm volatile("s_barrier" ::: "memory");
    __builtin_amdgcn_s_setprio(1);
    phase_mac<3>(acc, af, bg1);
    __builtin_amdgcn_s_setprio(0);
  }

  // tile 63 (buf 1), no staging, no barriers needed
  {
    f16x8 af[4][2], bg0[2][2], bg1[2][2];
    read_af<0>(sA[1], wr, r16, quad, af);
    read_bg<0>(sB[1], wc, r16, quad, bg0);
    read_bg<1>(sB[1], wc, r16, quad, bg1);
    phase_mac<0>(acc, af, bg0);
    phase_mac<1>(acc, af, bg1);
    read_af<1>(sA[1], wr, r16, quad, af);
    phase_mac<2>(acc, af, bg0);
    phase_mac<3>(acc, af, bg1);
  }

  // epilogue: per-row max over the full 256-wide block -> atomicMax
#pragma unroll
  for (int qm = 0; qm < 2; qm++)
#pragma unroll
    for (int i = 0; i < 4; i++)
#pragma unroll
      for (int r = 0; r < 4; r++) {
        float mv = acc[qm * 2][i][0][r];
        mv = fmaxf(mv, acc[qm * 2][i][1][r]);
        mv = fmaxf(mv, acc[qm * 2 + 1][i][0][r]);
        mv = fmaxf(mv, acc[qm * 2 + 1][i][1][r]);
        for (int off = 1; off < 16; off <<= 1) mv = fmaxf(mv, __shfl_xor(mv, off, 64));
        if (r16 == 0) {
          int row = m0 + qm * 128 + wr * 64 + i * 16 + quad * 4 + r;
          atomicMax((unsigned int*)&rowMax[row], __float_as_uint(mv));
        }
      }
  // fp16 store of the tile
#pragma unroll
  for (int p = 0; p < 4; p++) {
    const int qm = p >> 1, qn = p & 1;
#pragma unroll
    for (int i = 0; i < 4; i++)
#pragma unroll
      for (int j = 0; j < 2; j++)
#pragma unroll
        for (int r = 0; r < 4; r++) {
          int row = m0 + qm * 128 + wr * 64 + i * 16 + quad * 4 + r;
          int col = p0 + qn * 128 + wc * 32 + j * 16 + r16;
          Sh[(size_t)row * NN_ + col] = (_Float16)acc[p][i][j][r];
        }
  }
}

// ---------------------------------------------------------------------------
// Kernel 5: one BLOCK (4 waves) per row. Each wave scans 1/4 of the S~ row
// for candidates (S~ > rowMax-16) into a shared list; candidates are then
// distributed across waves (j = wave, wave+4, ...), each wave keeping its own
// online-softmax state (m, l, o); final flash-merge via LDS. Exact candidate
// scores: fp32 dot of (Ah+Al) x (Rth+Rtl), 64-lane shuffle reduce.
// ---------------------------------------------------------------------------
__global__ __launch_bounds__(256) void refine_kernel(const _Float16* __restrict__ Sh,
                                                     const float* __restrict__ rowMax,
                                                     const _Float16* __restrict__ Ah,
                                                     const _Float16* __restrict__ Al,
                                                     const _Float16* __restrict__ Rth,
                                                     const _Float16* __restrict__ Rtl,
                                                     const float* __restrict__ Vf,
                                                     float* __restrict__ out, int h) {
  __shared__ int plist[64];
  __shared__ int cnt;
  __shared__ float mW[4], lW[4];
  __shared__ float oW[4][32];
  const int t = threadIdx.x;
  const int wave = t >> 6, lane = t & 63;
  const int n = blockIdx.x;
  if (t == 0) cnt = 0;
  __syncthreads();
  const float thr = rowMax[n] - 16.0f;
  const _Float16* srow = Sh + (size_t)n * NN_;
  // each wave scans 2 of the 8 chunks (1024 elements)
  for (int q = 0; q < 2; q++) {
    int it = wave * 2 + q;
    f16x8 v = *(const f16x8*)&srow[it * 512 + lane * 8];
#pragma unroll
    for (int e = 0; e < 8; e++) {
      if ((float)v[e] > thr) {
        int idx = atomicAdd(&cnt, 1);
        if (idx < 64) plist[idx] = it * 512 + lane * 8 + e;
      }
    }
  }
  __syncthreads();
  int C = cnt;
  if (C > 64) C = 64;
  const _Float16* arh = Ah + (size_t)n * NN_;
  const _Float16* arl = Al + (size_t)n * NN_;
  float mcur = -1e30f, lsum = 0.f, oacc = 0.f;
  for (int j = wave; j < C; j += 4) {
    int p = plist[j];
    const _Float16* rh = Rth + (size_t)p * NN_;
    const _Float16* rl = Rtl + (size_t)p * NN_;
    float d = 0.f;
#pragma unroll
    for (int it = 0; it < 8; it++) {
      int m = it * 512 + lane * 8;
      f16x8 a8 = *(const f16x8*)&arh[m];
      f16x8 l8 = *(const f16x8*)&arl[m];
      f16x8 c8 = *(const f16x8*)&rh[m];
      f16x8 e8 = *(const f16x8*)&rl[m];
#pragma unroll
      for (int e = 0; e < 8; e++)
        d += ((float)a8[e] + (float)l8[e]) * ((float)c8[e] + (float)e8[e]);
    }
    for (int off = 32; off > 0; off >>= 1) d += __shfl_xor(d, off, 64);
    float vval = (lane < 32) ? Vf[(size_t)p * DM_ + h * 32 + lane] : 0.f;
    float nm = fmaxf(mcur, d);
    float alpha = __expf(mcur - nm);
    float w = __expf(d - nm);
    lsum = lsum * alpha + w;
    oacc = oacc * alpha + w * vval;
    mcur = nm;
  }
  if (lane == 0) { mW[wave] = mcur; lW[wave] = lsum; }
  if (lane < 32) oW[wave][lane] = oacc;
  __syncthreads();
  if (wave == 0 && lane < 32) {
    float M = fmaxf(fmaxf(mW[0], mW[1]), fmaxf(mW[2], mW[3]));
    float l = 0.f, o = 0.f;
#pragma unroll
    for (int w = 0; w < 4; w++) {
      float al = __expf(mW[w] - M);
      l += lW[w] * al;
      o += oW[w][lane] * al;
    }
    out[(size_t)n * DM_ + h * 32 + lane] = o / l;
  }
}

// ---------------------------------------------------------------------------
extern "C" void kernel_launch(void* const* d_in, const int* in_sizes, int n_in,
                              void* d_out, int out_size, void* d_ws, size_t ws_size,
                              hipStream_t stream) {
  const float* inQ = (const float*)d_in[0];
  const float* inK = (const float*)d_in[1];
  const float* inV = (const float*)d_in[2];
  // d_in[3] = adj_matrix: dead code in the reference
  const float* dist = (const float*)d_in[4];
  const float* WQ = (const float*)d_in[5];
  const float* WK = (const float*)d_in[6];
  const float* WV = (const float*)d_in[7];
  float* out = (float*)d_out;

  const size_t ND = (size_t)NN_ * DM_;   // 1M
  const size_t NSQ = (size_t)NN_ * NN_;  // 16.7M
  // ws layout (~172 MiB total; 212 MiB proven available in round 1):
  float* Vf = (float*)d_ws;              // 4 MiB
  ushort_t* Q1 = (ushort_t*)(Vf + ND);   // 2 MiB each
  ushort_t* Q2 = Q1 + ND;
  ushort_t* K1 = Q2 + ND;
  ushort_t* K2 = K1 + ND;
  _Float16* Rth = (_Float16*)(K2 + ND);  // 32 MiB each
  _Float16* Rtl = Rth + NSQ;
  _Float16* Ah = Rtl + NSQ;              // per-head reuse, 32 MiB each
  _Float16* Al = Ah + NSQ;
  _Float16* Sh = Al + NSQ;               // 32 MiB
  float* rowMax = (float*)(Sh + NSQ);    // 16 KiB

  rescale_kernel<<<dim3(64, 64), 256, 0, stream>>>(dist, Rth, Rtl);
  proj_kernel<<<dim3(4, 64), 256, 0, stream>>>(inQ, WQ, (float*)nullptr, Q1, Q2);
  proj_kernel<<<dim3(4, 64), 256, 0, stream>>>(inK, WK, (float*)nullptr, K1, K2);
  proj_kernel<<<dim3(4, 64), 256, 0, stream>>>(inV, WV, Vf, (ushort_t*)nullptr, (ushort_t*)nullptr);
  for (int h = 0; h < 8; h++) {
    qk_kernel<<<dim3(64, 64), 256, 0, stream>>>(Q1, Q2, K1, K2, Ah, Al, rowMax, h);
    sgemm_kernel<<<dim3(256), dim3(512), 0, stream>>>(Ah, Rth, Sh, rowMax);
    refine_kernel<<<NN_, 256, 0, stream>>>(Sh, rowMax, Ah, Al, Rth, Rtl, Vf, out, h);
  }
}

// Round 8
// 1851.202 us; speedup vs baseline: 1.0438x; 1.0076x over previous
//
#include <hip/hip_runtime.h>
#include <stdint.h>

#define NN_ 4096
#define DM_ 256

typedef unsigned short ushort_t;
typedef __bf16 bf16x8 __attribute__((ext_vector_type(8)));
typedef _Float16 f16x8 __attribute__((ext_vector_type(8)));
typedef float f32x4 __attribute__((ext_vector_type(4)));

__device__ __forceinline__ unsigned short f32_to_bf16(float x) {
  unsigned int u = __float_as_uint(x);
  unsigned int r = u + 0x7FFFu + ((u >> 16) & 1u);   // RNE
  return (unsigned short)(r >> 16);
}
__device__ __forceinline__ float bf16_to_f32(unsigned short h) {
  return __uint_as_float(((unsigned int)h) << 16);
}

// global -> LDS direct (16B/lane). LDS dest is wave-uniform base + lane*16.
__device__ __forceinline__ void async_cp16(const void* g, void* l) {
  auto gp = reinterpret_cast<__attribute__((address_space(1))) unsigned int*>(
      reinterpret_cast<uintptr_t>(g));
  auto lp = reinterpret_cast<__attribute__((address_space(3))) unsigned int*>(
      reinterpret_cast<uintptr_t>(l));
  __builtin_amdgcn_global_load_lds(gp, lp, 16, 0, 0);
}

// ---------------------------------------------------------------------------
// Kernel 1: Rt = rescale(dist)^T as fp16 hi/lo pair. Rt[p][m] = f(dist[m][p]).
// ---------------------------------------------------------------------------
__global__ __launch_bounds__(256) void rescale_kernel(const float* __restrict__ dist,
                                                      _Float16* __restrict__ Rth,
                                                      _Float16* __restrict__ Rtl) {
  __shared__ float tile[64][65];
  const int m0 = blockIdx.y * 64;
  const int p0 = blockIdx.x * 64;
  const int t = threadIdx.x;
  const int c = t & 63;
  const int rg = t >> 6;
  const float C = 3.718281828459045f;  // 1 + e
  for (int i = 0; i < 16; i++) {
    int ml = rg * 16 + i;
    float d = dist[(size_t)(m0 + ml) * NN_ + p0 + c];
    tile[c][ml] = C / (1.0f + expf(1.0f - d));  // store transposed into LDS
  }
  __syncthreads();
  for (int i = 0; i < 16; i++) {
    int pl = rg * 16 + i;
    float v = tile[pl][c];
    _Float16 hv = (_Float16)v;
    size_t o = (size_t)(p0 + pl) * NN_ + m0 + c;
    Rth[o] = hv;
    Rtl[o] = (_Float16)(v - (float)hv);
  }
}

// ---------------------------------------------------------------------------
// Kernel 2: O = X @ W^T (fp32 accum). Optional fp32 out, optional bf16 hi/lo.
// ---------------------------------------------------------------------------
__global__ __launch_bounds__(256) void proj_kernel(const float* __restrict__ X,
                                                   const float* __restrict__ W,
                                                   float* __restrict__ Of,
                                                   ushort_t* __restrict__ O1,
                                                   ushort_t* __restrict__ O2) {
  __shared__ float Xs[64][33];
  __shared__ float Ws[64][33];
  const int m0 = blockIdx.y * 64;
  const int n0 = blockIdx.x * 64;
  const int t = threadIdx.x;
  const int tm = t >> 4, tn = t & 15;
  float acc[4][4] = {};
  for (int k0 = 0; k0 < DM_; k0 += 32) {
    for (int q = 0; q < 2; q++) {
      int id = t + q * 256;
      int row = id >> 3;
      int c4 = (id & 7) * 4;
      float4 vx = *(const float4*)&X[(size_t)(m0 + row) * DM_ + k0 + c4];
      Xs[row][c4] = vx.x; Xs[row][c4 + 1] = vx.y; Xs[row][c4 + 2] = vx.z; Xs[row][c4 + 3] = vx.w;
      float4 vw = *(const float4*)&W[(size_t)(n0 + row) * DM_ + k0 + c4];
      Ws[row][c4] = vw.x; Ws[row][c4 + 1] = vw.y; Ws[row][c4 + 2] = vw.z; Ws[row][c4 + 3] = vw.w;
    }
    __syncthreads();
    for (int kk = 0; kk < 32; kk++) {
      float xi[4], wj[4];
      for (int i = 0; i < 4; i++) xi[i] = Xs[tm * 4 + i][kk];
      for (int j = 0; j < 4; j++) wj[j] = Ws[tn * 4 + j][kk];
      for (int i = 0; i < 4; i++)
        for (int j = 0; j < 4; j++) acc[i][j] += xi[i] * wj[j];
    }
    __syncthreads();
  }
  for (int i = 0; i < 4; i++)
    for (int j = 0; j < 4; j++) {
      size_t o = (size_t)(m0 + tm * 4 + i) * DM_ + n0 + tn * 4 + j;
      float v = acc[i][j];
      if (Of != nullptr) Of[o] = v;
      if (O1 != nullptr) {
        unsigned short hh = f32_to_bf16(v);
        O1[o] = hh;
        O2[o] = f32_to_bf16(v - bf16_to_f32(hh));
      }
    }
}

// ---------------------------------------------------------------------------
// Kernel 3: per head, A = relu(Q_h K_h^T)/sqrt(32), 3-product bf16 (exact-ish),
// output as fp16 hi/lo pair. Block (0,0) also zeroes rowMax for this head.
// ---------------------------------------------------------------------------
__global__ __launch_bounds__(256) void qk_kernel(const ushort_t* __restrict__ Q1,
                                                 const ushort_t* __restrict__ Q2,
                                                 const ushort_t* __restrict__ K1,
                                                 const ushort_t* __restrict__ K2,
                                                 _Float16* __restrict__ Ah,
                                                 _Float16* __restrict__ Al,
                                                 float* __restrict__ rowMax, int h) {
  const int n0 = blockIdx.y * 64;  // rows (n, from Q)
  const int m0 = blockIdx.x * 64;  // cols (m, from K)
  const int t = threadIdx.x;
  if (blockIdx.x == 0 && blockIdx.y == 0) {
    for (int i = t; i < NN_; i += 256) rowMax[i] = 0.f;
  }
  const int wave = t >> 6, lane = t & 63;
  const int wm = wave >> 1, wn = wave & 1;
  const int r16 = lane & 15, quad = lane >> 4;
  const int ho = h * 32 + quad * 8;
  f32x4 acc[2][2] = {};
  bf16x8 a1[2], a2[2], b1[2], b2[2];
  for (int i = 0; i < 2; i++) {
    int row = n0 + wm * 32 + i * 16 + r16;
    a1[i] = *(const bf16x8*)&Q1[(size_t)row * DM_ + ho];
    a2[i] = *(const bf16x8*)&Q2[(size_t)row * DM_ + ho];
  }
  for (int j = 0; j < 2; j++) {
    int col = m0 + wn * 32 + j * 16 + r16;
    b1[j] = *(const bf16x8*)&K1[(size_t)col * DM_ + ho];
    b2[j] = *(const bf16x8*)&K2[(size_t)col * DM_ + ho];
  }
  for (int i = 0; i < 2; i++)
    for (int j = 0; j < 2; j++) {
      acc[i][j] = __builtin_amdgcn_mfma_f32_16x16x32_bf16(a1[i], b1[j], acc[i][j], 0, 0, 0);
      acc[i][j] = __builtin_amdgcn_mfma_f32_16x16x32_bf16(a1[i], b2[j], acc[i][j], 0, 0, 0);
      acc[i][j] = __builtin_amdgcn_mfma_f32_16x16x32_bf16(a2[i], b1[j], acc[i][j], 0, 0, 0);
    }
  const float scale = 0.17677669529663688f;  // 1/sqrt(32)
  for (int i = 0; i < 2; i++)
    for (int j = 0; j < 2; j++)
      for (int r = 0; r < 4; r++) {
        int row = n0 + wm * 32 + i * 16 + quad * 4 + r;  // C/D: col=lane&15, row=quad*4+reg
        int col = m0 + wn * 32 + j * 16 + r16;
        float w = acc[i][j][r] * scale;
        w = w > 0.f ? w : 0.f;
        _Float16 hh = (_Float16)w;
        size_t o = (size_t)row * NN_ + col;
        Ah[o] = hh;
        Al[o] = (_Float16)(w - (float)hh);
      }
}

// ---------------------------------------------------------------------------
// Kernel 4: S~ = Ah @ Rth^T (NT, K=4096), fp16 MFMA.
// 256x256 tile, BK=64, 512 threads (8 waves, 2Mx4N).
// Round-8 schedule: 8 REGIONS of 8 MFMA per K-tile with WITHIN-WAVE read-ahead
// (the m201/m196 "per-phase interleave" lever): each region issues the NEXT
// region's ds_reads BEFORE its own MFMA cluster, so the LDS pipe drains while
// the matrix pipe is busy (rounds 3-7 showed them SUMMING: reads were in
// program order AFTER the MFMA block, and 2-wave/SIMD matrix serialization +
// barriers kept all waves' reads clumped between MFMA windows).
// Fragment quarters rotate through 2 sets each (a0q/a1q, b0g/b1g = 64 VGPR,
// same as before; full dual-af would need +32 and break 8-wave occupancy).
// Read distribution/region: 4,4,0,4,4,0,4,4 (CU burst 384cy vs 310cy MFMA
// window; empty regions absorb). Lifetimes: every overwrite lands >=1 region
// after the old value's last MAC. Boundary: vmcnt(0)+barrier at region 6;
// regions 6/7 then read next tile's bg0'/a00' from the confirmed buffer.
// Staging (8 gload_lds) spread 2/region over regions 0-3.
// LDS: 2 x (A 256x64 + B 256x64) fp16 = 128 KiB. Chunk-XOR swizzle
// (0-conflict proven): chunk c of row r at slot c^(r&7); staging pre-swizzles
// the per-lane GLOBAL chunk (lane&7)^srow. setprio(1) around MFMA clusters.
// ---------------------------------------------------------------------------
template <int SLOT>
__device__ __forceinline__ void stage_half(const _Float16* __restrict__ Ah,
                                           const _Float16* __restrict__ Rth,
                                           int m0, int p0, _Float16* sAY, _Float16* sBY,
                                           int tn, int wave, int srow, int cg) {
  const _Float16* src = (SLOT == 0 || SLOT == 3) ? Ah : Rth;
  const int gr0 = ((SLOT == 0 || SLOT == 3) ? m0 : p0) + ((SLOT >= 2) ? 128 : 0);
  _Float16* dst = ((SLOT == 0 || SLOT == 3) ? sAY : sBY) + ((SLOT >= 2) ? 128 * 64 : 0);
  const int k0 = tn * 64;
#pragma unroll
  for (int q = 0; q < 2; q++) {
    const int rl = wave * 16 + q * 8;  // wave-uniform slab base (8 rows x 64 f16)
    async_cp16(&src[(size_t)(gr0 + rl + srow) * NN_ + k0 + cg * 8], dst + rl * 64);
  }
}

// read one A quarter: QM half, H row-pair (2 rows of 16 x full K=64) -> 4 reads
template <int QM, int H>
__device__ __forceinline__ void read_aq(const _Float16* sAX, int wr, int r16, int quad,
                                        f16x8 (&aq)[2][2]) {
#pragma unroll
  for (int i2 = 0; i2 < 2; i2++) {
    int ar = QM * 128 + wr * 64 + (H * 2 + i2) * 16 + r16;
    const _Float16* base = sAX + ar * 64;
    int x = ar & 7;
    aq[i2][0] = *(const f16x8*)(base + (quad ^ x) * 8);
    aq[i2][1] = *(const f16x8*)(base + ((4 + quad) ^ x) * 8);
  }
}

template <int QN>
__device__ __forceinline__ void read_bg(const _Float16* sBX, int wc, int r16, int quad,
                                        f16x8 (&bg)[2][2]) {
#pragma unroll
  for (int j = 0; j < 2; j++) {
    int br = QN * 128 + wc * 32 + j * 16 + r16;
    const _Float16* base = sBX + br * 64;
    int x = br & 7;
    bg[j][0] = *(const f16x8*)(base + (quad ^ x) * 8);
    bg[j][1] = *(const f16x8*)(base + ((4 + quad) ^ x) * 8);
  }
}

// 8 MFMA: quadrant P, row-half H (rows H*2+0, H*2+1 of acc[P])
template <int P, int H>
__device__ __forceinline__ void mac8(f32x4 (&acc)[4][4][2],
                                     f16x8 (&aq)[2][2], f16x8 (&bg)[2][2]) {
#pragma unroll
  for (int i2 = 0; i2 < 2; i2++)
#pragma unroll
    for (int j = 0; j < 2; j++) {
      acc[P][H * 2 + i2][j] =
          __builtin_amdgcn_mfma_f32_16x16x32_f16(aq[i2][0], bg[j][0], acc[P][H * 2 + i2][j], 0, 0, 0);
      acc[P][H * 2 + i2][j] =
          __builtin_amdgcn_mfma_f32_16x16x32_f16(aq[i2][1], bg[j][1], acc[P][H * 2 + i2][j], 0, 0, 0);
    }
}

#define SGEMM_BAR asm volatile("s_barrier" ::: "memory")
#define SGEMM_VM0 asm volatile("s_waitcnt vmcnt(0)" ::: "memory")

__global__ __launch_bounds__(512, 2) void sgemm_kernel(const _Float16* __restrict__ Ah,
                                                       const _Float16* __restrict__ Rth,
                                                       _Float16* __restrict__ Sh,
                                                       float* __restrict__ rowMax) {
  __shared__ _Float16 sA[2][256 * 64];  // 32 KB per buffer
  __shared__ _Float16 sB[2][256 * 64];
  // XCD-aware bijective swizzle: 256 wgs, 8 XCDs, 32 contiguous tiles per XCD.
  const int b = blockIdx.x;
  const int swz = (b & 7) * 32 + (b >> 3);
  const int m0 = (swz >> 4) * 256;
  const int p0 = (swz & 15) * 256;
  const int tid = threadIdx.x;
  const int wave = tid >> 6, lane = tid & 63;
  const int wr = wave >> 2, wc = wave & 3;   // 2M x 4N wave grid
  const int r16 = lane & 15, quad = lane >> 4;
  const int srow = lane >> 3;            // row within 8-row staging slab
  const int cg = (lane & 7) ^ srow;      // pre-swizzled global chunk

  f32x4 acc[4][4][2] = {};               // [quadrant][i][j]
  f16x8 a0q[2][2], a1q[2][2];            // rotating A-quarter sets (16 VGPR each)
  f16x8 b0g[2][2], b1g[2][2];            // B halves (16 VGPR each)

  // prologue: stage tile 0, confirm, preload a00 + bg0
  stage_half<0>(Ah, Rth, m0, p0, sA[0], sB[0], 0, wave, srow, cg);
  stage_half<1>(Ah, Rth, m0, p0, sA[0], sB[0], 0, wave, srow, cg);
  stage_half<2>(Ah, Rth, m0, p0, sA[0], sB[0], 0, wave, srow, cg);
  stage_half<3>(Ah, Rth, m0, p0, sA[0], sB[0], 0, wave, srow, cg);
  SGEMM_VM0;
  SGEMM_BAR;
  read_bg<0>(sB[0], wc, r16, quad, b0g);
  read_aq<0, 0>(sA[0], wr, r16, quad, a0q);

  for (int tt = 0; tt < 63; ++tt) {
    const int X = tt & 1, Y = X ^ 1;
    const _Float16* sAX = sA[X];
    const _Float16* sBX = sB[X];
    // r0: read a01 -> a1q; stage slot0; m0 = a00*bg0
    read_aq<0, 1>(sAX, wr, r16, quad, a1q);
    stage_half<0>(Ah, Rth, m0, p0, sA[Y], sB[Y], tt + 1, wave, srow, cg);
    SGEMM_BAR;
    __builtin_amdgcn_s_setprio(1);
    mac8<0, 0>(acc, a0q, b0g);
    __builtin_amdgcn_s_setprio(0);
    // r1: read bg1 -> b1g; stage slot1; m1 = a01*bg0
    read_bg<1>(sBX, wc, r16, quad, b1g);
    stage_half<1>(Ah, Rth, m0, p0, sA[Y], sB[Y], tt + 1, wave, srow, cg);
    SGEMM_BAR;
    __builtin_amdgcn_s_setprio(1);
    mac8<0, 1>(acc, a1q, b0g);
    __builtin_amdgcn_s_setprio(0);
    // r2: no reads; stage slot2; m2 = a00*bg1
    stage_half<2>(Ah, Rth, m0, p0, sA[Y], sB[Y], tt + 1, wave, srow, cg);
    SGEMM_BAR;
    __builtin_amdgcn_s_setprio(1);
    mac8<1, 0>(acc, a0q, b1g);
    __builtin_amdgcn_s_setprio(0);
    // r3: read a10 -> a0q; stage slot3; m3 = a01*bg1
    read_aq<1, 0>(sAX, wr, r16, quad, a0q);
    stage_half<3>(Ah, Rth, m0, p0, sA[Y], sB[Y], tt + 1, wave, srow, cg);
    SGEMM_BAR;
    __builtin_amdgcn_s_setprio(1);
    mac8<1, 1>(acc, a1q, b1g);
    __builtin_amdgcn_s_setprio(0);
    // r4: read a11 -> a1q; m4 = a10*bg0
    read_aq<1, 1>(sAX, wr, r16, quad, a1q);
    SGEMM_BAR;
    __builtin_amdgcn_s_setprio(1);
    mac8<2, 0>(acc, a0q, b0g);
    __builtin_amdgcn_s_setprio(0);
    // r5: no reads; m5 = a11*bg0
    SGEMM_BAR;
    __builtin_amdgcn_s_setprio(1);
    mac8<2, 1>(acc, a1q, b0g);
    __builtin_amdgcn_s_setprio(0);
    // r6 (boundary): confirm next tile; read bg0' -> b0g; m6 = a10*bg1
    SGEMM_VM0;
    SGEMM_BAR;
    read_bg<0>(sB[Y], wc, r16, quad, b0g);
    __builtin_amdgcn_s_setprio(1);
    mac8<3, 0>(acc, a0q, b1g);
    __builtin_amdgcn_s_setprio(0);
    // r7: read a00' -> a0q; m7 = a11*bg1
    read_aq<0, 0>(sA[Y], wr, r16, quad, a0q);
    SGEMM_BAR;
    __builtin_amdgcn_s_setprio(1);
    mac8<3, 1>(acc, a1q, b1g);
    __builtin_amdgcn_s_setprio(0);
  }

  // tail: tile 63 from buf 1 (a00,bg0 already in a0q,b0g; no staging, no bars)
  {
    const _Float16* sAX = sA[1];
    const _Float16* sBX = sB[1];
    read_aq<0, 1>(sAX, wr, r16, quad, a1q);
    mac8<0, 0>(acc, a0q, b0g);
    read_bg<1>(sBX, wc, r16, quad, b1g);
    mac8<0, 1>(acc, a1q, b0g);
    mac8<1, 0>(acc, a0q, b1g);
    read_aq<1, 0>(sAX, wr, r16, quad, a0q);
    mac8<1, 1>(acc, a1q, b1g);
    read_aq<1, 1>(sAX, wr, r16, quad, a1q);
    mac8<2, 0>(acc, a0q, b0g);
    mac8<2, 1>(acc, a1q, b0g);
    mac8<3, 0>(acc, a0q, b1g);
    mac8<3, 1>(acc, a1q, b1g);
  }

  // epilogue: per-row max over the full 256-wide block -> atomicMax
#pragma unroll
  for (int qm = 0; qm < 2; qm++)
#pragma unroll
    for (int i = 0; i < 4; i++)
#pragma unroll
      for (int r = 0; r < 4; r++) {
        float mv = acc[qm * 2][i][0][r];
        mv = fmaxf(mv, acc[qm * 2][i][1][r]);
        mv = fmaxf(mv, acc[qm * 2 + 1][i][0][r]);
        mv = fmaxf(mv, acc[qm * 2 + 1][i][1][r]);
        for (int off = 1; off < 16; off <<= 1) mv = fmaxf(mv, __shfl_xor(mv, off, 64));
        if (r16 == 0) {
          int row = m0 + qm * 128 + wr * 64 + i * 16 + quad * 4 + r;
          atomicMax((unsigned int*)&rowMax[row], __float_as_uint(mv));
        }
      }
  // fp16 store of the tile
#pragma unroll
  for (int p = 0; p < 4; p++) {
    const int qm = p >> 1, qn = p & 1;
#pragma unroll
    for (int i = 0; i < 4; i++)
#pragma unroll
      for (int j = 0; j < 2; j++)
#pragma unroll
        for (int r = 0; r < 4; r++) {
          int row = m0 + qm * 128 + wr * 64 + i * 16 + quad * 4 + r;
          int col = p0 + qn * 128 + wc * 32 + j * 16 + r16;
          Sh[(size_t)row * NN_ + col] = (_Float16)acc[p][i][j][r];
        }
  }
}

// ---------------------------------------------------------------------------
// Kernel 5: one BLOCK (4 waves) per row. Each wave scans 1/4 of the S~ row
// for candidates (S~ > rowMax-16) into a shared list; candidates are then
// distributed across waves (j = wave, wave+4, ...), each wave keeping its own
// online-softmax state (m, l, o); final flash-merge via LDS. Exact candidate
// scores: fp32 dot of (Ah+Al) x (Rth+Rtl), 64-lane shuffle reduce.
// ---------------------------------------------------------------------------
__global__ __launch_bounds__(256) void refine_kernel(const _Float16* __restrict__ Sh,
                                                     const float* __restrict__ rowMax,
                                                     const _Float16* __restrict__ Ah,
                                                     const _Float16* __restrict__ Al,
                                                     const _Float16* __restrict__ Rth,
                                                     const _Float16* __restrict__ Rtl,
                                                     const float* __restrict__ Vf,
                                                     float* __restrict__ out, int h) {
  __shared__ int plist[64];
  __shared__ int cnt;
  __shared__ float mW[4], lW[4];
  __shared__ float oW[4][32];
  const int t = threadIdx.x;
  const int wave = t >> 6, lane = t & 63;
  const int n = blockIdx.x;
  if (t == 0) cnt = 0;
  __syncthreads();
  const float thr = rowMax[n] - 16.0f;
  const _Float16* srow = Sh + (size_t)n * NN_;
  // each wave scans 2 of the 8 chunks (1024 elements)
  for (int q = 0; q < 2; q++) {
    int it = wave * 2 + q;
    f16x8 v = *(const f16x8*)&srow[it * 512 + lane * 8];
#pragma unroll
    for (int e = 0; e < 8; e++) {
      if ((float)v[e] > thr) {
        int idx = atomicAdd(&cnt, 1);
        if (idx < 64) plist[idx] = it * 512 + lane * 8 + e;
      }
    }
  }
  __syncthreads();
  int C = cnt;
  if (C > 64) C = 64;
  const _Float16* arh = Ah + (size_t)n * NN_;
  const _Float16* arl = Al + (size_t)n * NN_;
  float mcur = -1e30f, lsum = 0.f, oacc = 0.f;
  for (int j = wave; j < C; j += 4) {
    int p = plist[j];
    const _Float16* rh = Rth + (size_t)p * NN_;
    const _Float16* rl = Rtl + (size_t)p * NN_;
    float d = 0.f;
#pragma unroll
    for (int it = 0; it < 8; it++) {
      int m = it * 512 + lane * 8;
      f16x8 a8 = *(const f16x8*)&arh[m];
      f16x8 l8 = *(const f16x8*)&arl[m];
      f16x8 c8 = *(const f16x8*)&rh[m];
      f16x8 e8 = *(const f16x8*)&rl[m];
#pragma unroll
      for (int e = 0; e < 8; e++)
        d += ((float)a8[e] + (float)l8[e]) * ((float)c8[e] + (float)e8[e]);
    }
    for (int off = 32; off > 0; off >>= 1) d += __shfl_xor(d, off, 64);
    float vval = (lane < 32) ? Vf[(size_t)p * DM_ + h * 32 + lane] : 0.f;
    float nm = fmaxf(mcur, d);
    float alpha = __expf(mcur - nm);
    float w = __expf(d - nm);
    lsum = lsum * alpha + w;
    oacc = oacc * alpha + w * vval;
    mcur = nm;
  }
  if (lane == 0) { mW[wave] = mcur; lW[wave] = lsum; }
  if (lane < 32) oW[wave][lane] = oacc;
  __syncthreads();
  if (wave == 0 && lane < 32) {
    float M = fmaxf(fmaxf(mW[0], mW[1]), fmaxf(mW[2], mW[3]));
    float l = 0.f, o = 0.f;
#pragma unroll
    for (int w = 0; w < 4; w++) {
      float al = __expf(mW[w] - M);
      l += lW[w] * al;
      o += oW[w][lane] * al;
    }
    out[(size_t)n * DM_ + h * 32 + lane] = o / l;
  }
}

// ---------------------------------------------------------------------------
extern "C" void kernel_launch(void* const* d_in, const int* in_sizes, int n_in,
                              void* d_out, int out_size, void* d_ws, size_t ws_size,
                              hipStream_t stream) {
  const float* inQ = (const float*)d_in[0];
  const float* inK = (const float*)d_in[1];
  const float* inV = (const float*)d_in[2];
  // d_in[3] = adj_matrix: dead code in the reference
  const float* dist = (const float*)d_in[4];
  const float* WQ = (const float*)d_in[5];
  const float* WK = (const float*)d_in[6];
  const float* WV = (const float*)d_in[7];
  float* out = (float*)d_out;

  const size_t ND = (size_t)NN_ * DM_;   // 1M
  const size_t NSQ = (size_t)NN_ * NN_;  // 16.7M
  // ws layout (~172 MiB total; 212 MiB proven available in round 1):
  float* Vf = (float*)d_ws;              // 4 MiB
  ushort_t* Q1 = (ushort_t*)(Vf + ND);   // 2 MiB each
  ushort_t* Q2 = Q1 + ND;
  ushort_t* K1 = Q2 + ND;
  ushort_t* K2 = K1 + ND;
  _Float16* Rth = (_Float16*)(K2 + ND);  // 32 MiB each
  _Float16* Rtl = Rth + NSQ;
  _Float16* Ah = Rtl + NSQ;              // per-head reuse, 32 MiB each
  _Float16* Al = Ah + NSQ;
  _Float16* Sh = Al + NSQ;               // 32 MiB
  float* rowMax = (float*)(Sh + NSQ);    // 16 KiB

  rescale_kernel<<<dim3(64, 64), 256, 0, stream>>>(dist, Rth, Rtl);
  proj_kernel<<<dim3(4, 64), 256, 0, stream>>>(inQ, WQ, (float*)nullptr, Q1, Q2);
  proj_kernel<<<dim3(4, 64), 256, 0, stream>>>(inK, WK, (float*)nullptr, K1, K2);
  proj_kernel<<<dim3(4, 64), 256, 0, stream>>>(inV, WV, Vf, (ushort_t*)nullptr, (ushort_t*)nullptr);
  for (int h = 0; h < 8; h++) {
    qk_kernel<<<dim3(64, 64), 256, 0, stream>>>(Q1, Q2, K1, K2, Ah, Al, rowMax, h);
    sgemm_kernel<<<dim3(256), dim3(512), 0, stream>>>(Ah, Rth, Sh, rowMax);
    refine_kernel<<<NN_, 256, 0, stream>>>(Sh, rowMax, Ah, Al, Rth, Rtl, Vf, out, h);
  }
}